// Round 7
// baseline (260.872 us; speedup 1.0000x reference)
//
#include <hip/hip_runtime.h>

// LearnedQueryAttention: B=8, L=4096, KD=512, ED=1024, H=8. All I/O fp32.
// Raw-reshape semantics: head h owns the contiguous flat slab
// f = h*(L+1)*(C/H) + row*(C/H) + d of per-batch [X_flat | bias]; only
// f >= L*C touches the bias token (head 7, rows 4089..4096).
//
// R6 counters: fused kernel 85us, VALU 7.5%, HBM 15%, occ 76% => latency-bound,
// ~1-2 loads in flight/wave. R7: static unrolled loops (clamped addresses),
// all 17 V float4s preloaded to registers before phase A (V latency hidden
// under K sweep), wave-shfl reductions (3 barriers total), 3 blocks/CU.
#define BATCH 8
#define LSEQ  4096
#define LP    4097
#define KDIM  512
#define EDIM  1024
#define NH    8
#define DK    64
#define DV    128
#define NG    64          // B*H groups
#define NC    32          // chunks per group
#define RC    129         // rows per chunk (32*129 = 4128 >= 4097; chunk31 = 98)
#define RPAD  144         // 9*16 phase-A padded rows
#define LN_EPS 1e-5f

typedef float floatx4 __attribute__((ext_vector_type(4)));

// ---------------------------------------------------------------------------
// Kernel 1 (fused, MLP-optimized). Grid (32, 64), 256 thr.
// ---------------------------------------------------------------------------
__global__ __launch_bounds__(256, 3) void lqa_fused_kernel(
    const float* __restrict__ keys, const float* __restrict__ k_bias,
    const float* __restrict__ values, const float* __restrict__ v_bias,
    const float* __restrict__ query, const float* __restrict__ sw,
    const float* __restrict__ sb, float* __restrict__ partials,
    float2* __restrict__ stats)
{
    const int chunk = blockIdx.x;            // 0..31
    const int g = blockIdx.y;                // 0..63
    const int b = g >> 3, h = g & 7;
    const int t = threadIdx.x;
    const int wave = t >> 6;                 // 0..3
    const int lane = t & 63;

    const int row0 = chunk * RC;
    const int nrows = min(LP, row0 + RC) - row0;   // 129, or 98 for chunk 31

    __shared__ float ts[RPAD];
    __shared__ float red1[8];
    __shared__ float red2[4 * 128];

    // ---- Phase 0: issue all 17 V loads into registers (addresses clamped
    //      in-bounds; padded rows get zero weight later). 8 row-subsets. ----
    const int srow = t >> 5;                 // 0..7
    const int d0v = (t & 31) * 4;            // 0..124
    const float* vp = values + (long long)b * (LSEQ * EDIM);
    const int fheadv = h * (LP * DV);
    floatx4 vreg[17];
#pragma unroll
    for (int k = 0; k < 17; ++k) {
        const int row = min(row0 + srow + 8 * k, LP - 1);
        const int f = fheadv + row * DV + d0v;
        vreg[k] = (f < LSEQ * EDIM)
            ? *reinterpret_cast<const floatx4*>(vp + f)
            : *reinterpret_cast<const floatx4*>(v_bias + (f - LSEQ * EDIM));
    }

    // ---- Phase A: scores for this chunk into LDS (9 static iters). ----
    const int lane16 = t & 15;
    const int d0k = lane16 * 4;
    const floatx4 q = *reinterpret_cast<const floatx4*>(query + h * DK + d0k);
    const float* kp = keys + (long long)b * (LSEQ * KDIM);
    const int fheadk = h * (LP * DK);
    const float* w = sw + h * LP;
    const float* bb = sb + h * LP;

    float mloc = -1e30f;
#pragma unroll
    for (int kk = 0; kk < 9; ++kk) {
        const int r = (t >> 4) + 16 * kk;    // 0..143, each covered once
        const int row = min(row0 + r, LP - 1);
        const int f = fheadk + row * DK + d0k;
        const floatx4 kv = (f < LSEQ * KDIM)
            ? *reinterpret_cast<const floatx4*>(kp + f)
            : *reinterpret_cast<const floatx4*>(k_bias + (f - LSEQ * KDIM));
        float s = q.x * kv.x + q.y * kv.y + q.z * kv.z + q.w * kv.w;
        s += __shfl_xor(s, 1);
        s += __shfl_xor(s, 2);
        s += __shfl_xor(s, 4);
        s += __shfl_xor(s, 8);
        if (lane16 == 0) {
            const float tv = (r < nrows) ? s * w[row] + bb[row] : -1e30f;
            ts[r] = tv;
            mloc = fmaxf(mloc, tv);
        }
    }
    // block max: wave shfl-reduce (only lane16==0 hold real values; rest -1e30)
#pragma unroll
    for (int off = 1; off < 64; off <<= 1)
        mloc = fmaxf(mloc, __shfl_xor(mloc, off));
    if (lane == 0) red1[wave] = mloc;
    __syncthreads();                          // ts written + red1[0..3]
    const float mc = fmaxf(fmaxf(red1[0], red1[1]), fmaxf(red1[2], red1[3]));

    // convert ts -> exp(ts - mc); z partial
    float zloc = 0.f;
    if (t < RPAD) {
        const float e = __expf(ts[t] - mc);   // padded rows: exp(-1e30-mc)=0
        ts[t] = e;
        zloc = e;
    }
#pragma unroll
    for (int off = 1; off < 64; off <<= 1)
        zloc += __shfl_xor(zloc, off);
    if (lane == 0) red1[4 + wave] = zloc;
    __syncthreads();                          // ts converted + red1[4..7]
    const float zc = red1[4] + red1[5] + red1[6] + red1[7];

    // ---- Phase B: weighted V FMA from registers (V arrived during phase A) ----
    float acc[4] = {0.f, 0.f, 0.f, 0.f};
#pragma unroll
    for (int k = 0; k < 17; ++k) {
        const float wgt = ts[srow + 8 * k];   // max index 135 < RPAD
        acc[0] += wgt * vreg[k].x; acc[1] += wgt * vreg[k].y;
        acc[2] += wgt * vreg[k].z; acc[3] += wgt * vreg[k].w;
    }
    // pair-reduce srow and srow^1 within wave (lanes t and t^32)
#pragma unroll
    for (int j = 0; j < 4; ++j) acc[j] += __shfl_xor(acc[j], 32);
    if (lane < 32) {
#pragma unroll
        for (int j = 0; j < 4; ++j) red2[wave * 128 + lane * 4 + j] = acc[j];
    }
    __syncthreads();
    if (t < 128) {
        const float sum = red2[t] + red2[128 + t] + red2[256 + t] + red2[384 + t];
        partials[((long long)(g * NC + chunk)) * DV + t] = sum;
    }
    if (t == 0) stats[g * NC + chunk] = make_float2(mc, zc);
}

// ---------------------------------------------------------------------------
// Kernel 2: cross-chunk softmax combine + LayerNorm. One block per batch.
// ---------------------------------------------------------------------------
__global__ __launch_bounds__(256) void lqa_combine_ln_kernel(
    const float* __restrict__ partials, const float2* __restrict__ stats,
    const float* __restrict__ gamma, const float* __restrict__ beta,
    float* __restrict__ out)
{
    const int b = blockIdx.x;
    const int t = threadIdx.x;
    __shared__ float mh[NH], zh[NH];
    __shared__ float wc[NH * NC];
    __shared__ float r1[256], r2[256];

    if (t < NH) {
        const float2* st = stats + (b * NH + t) * NC;
        float m = -1e30f, Z = 0.f;
#pragma unroll
        for (int c = 0; c < NC; ++c) {
            const float2 s = st[c];
            const float mn = fmaxf(m, s.x);
            Z = Z * __expf(m - mn) + s.y * __expf(s.x - mn);
            m = mn;
        }
        mh[t] = m; zh[t] = Z;
    }
    __syncthreads();
    {
        const int h = t >> 5, c = t & 31;
        const float2 s = stats[(b * NH + h) * NC + c];
        wc[t] = __expf(s.x - mh[h]) / zh[h];
    }
    __syncthreads();

    float a[4];
    float s1 = 0.f, s2 = 0.f;
#pragma unroll
    for (int i = 0; i < 4; ++i) {
        const int e = t + i * 256;
        const int h = e >> 7, d = e & 127;
        const float* src = partials + ((long long)((b * NH + h) * NC)) * DV + d;
        const float* wr = wc + h * NC;
        float sum = 0.f;
#pragma unroll
        for (int c = 0; c < NC; ++c) sum += src[c * DV] * wr[c];
        a[i] = sum;
        s1 += sum;
        s2 += sum * sum;
    }
    r1[t] = s1; r2[t] = s2; __syncthreads();
    for (int off = 128; off > 0; off >>= 1) {
        if (t < off) { r1[t] += r1[t + off]; r2[t] += r2[t + off]; }
        __syncthreads();
    }
    const float mean = r1[0] * (1.0f / EDIM);
    const float var = r2[0] * (1.0f / EDIM) - mean * mean;
    const float inv = rsqrtf(var + LN_EPS);
#pragma unroll
    for (int i = 0; i < 4; ++i) {
        const int e = t + i * 256;
        out[(long long)b * EDIM + e] = (a[i] - mean) * inv * gamma[e] + beta[e];
    }
}

// ---------------------------------------------------------------------------
extern "C" void kernel_launch(void* const* d_in, const int* in_sizes, int n_in,
                              void* d_out, int out_size, void* d_ws, size_t ws_size,
                              hipStream_t stream) {
    const float* keys   = (const float*)d_in[0];
    const float* values = (const float*)d_in[1];
    const float* query  = (const float*)d_in[2];
    const float* k_bias = (const float*)d_in[3];
    const float* v_bias = (const float*)d_in[4];
    const float* sw     = (const float*)d_in[5];
    const float* sb     = (const float*)d_in[6];
    const float* gamma  = (const float*)d_in[7];
    const float* beta   = (const float*)d_in[8];
    float* out = (float*)d_out;

    // ws layout (floats): partials[64][32][128] | stats[64*32] float2 (~1.1 MB)
    float* ws = (float*)d_ws;
    float* partials = ws;
    float2* stats = (float2*)(ws + (long long)NG * NC * DV);

    lqa_fused_kernel<<<dim3(NC, NG), 256, 0, stream>>>(
        keys, k_bias, values, v_bias, query, sw, sb, partials, stats);
    lqa_combine_ln_kernel<<<BATCH, 256, 0, stream>>>(
        partials, stats, gamma, beta, out);
}